// Round 1
// baseline (112.653 us; speedup 1.0000x reference)
//
#include <hip/hip_runtime.h>

#define S_ROWS 2048
#define RO_ROWS 8192
#define HEADS 8
#define HDIM 32
#define ROWLEN 256   // HEADS * HDIM

typedef __attribute__((ext_vector_type(8))) short bf16x8;
typedef __attribute__((ext_vector_type(4))) float f32x4;

// Normalize every 32-element head vector of both inputs, emit bf16.
// Grid covers (S_ROWS+RO_ROWS)*ROWLEN elements exactly; each 32-lane group
// owns one head vector (idx%32 == threadIdx.x%32, so shfl_xor<=16 stays
// inside the vector's lane group).
__global__ __launch_bounds__(256) void mhd_normalize(const float* __restrict__ s,
                                                     const float* __restrict__ ro,
                                                     short* __restrict__ outN) {
    const int idx = blockIdx.x * 256 + threadIdx.x;
    const int S_TOT = S_ROWS * ROWLEN;
    float x = (idx < S_TOT) ? s[idx] : ro[idx - S_TOT];
    float ss = x * x;
    ss += __shfl_xor(ss, 1);
    ss += __shfl_xor(ss, 2);
    ss += __shfl_xor(ss, 4);
    ss += __shfl_xor(ss, 8);
    ss += __shfl_xor(ss, 16);
    const float y = x * rsqrtf(ss);
    union { float f; unsigned u; } v; v.f = y;
    // round-to-nearest-even f32 -> bf16
    const unsigned short r =
        (unsigned short)((v.u + 0x7fffu + ((v.u >> 16) & 1u)) >> 16);
    outN[idx] = (short)r;
}

// Each wave computes a 64x64 output tile: per head, 4 A-frags x 4 B-frags,
// 16 MFMAs (16x16x32, K=32 == HDIM exactly, C=0), then elementwise max into
// the running max. A/B frag: lane reads 8 contiguous bf16 at
// [row|col = base + (lane&15)][head*32 + (lane>>4)*8] — same k-bijection for
// both operands => correct dot product. D: row=(lane>>4)*4+q, col=lane&15.
__global__ __launch_bounds__(256) void mhd_dist(const short* __restrict__ sN,
                                                const short* __restrict__ roN,
                                                float* __restrict__ out) {
    const int lane = threadIdx.x & 63;
    const int wave = threadIdx.x >> 6;   // 4 waves: 2x2 of 64x64 tiles
    const int wr = wave >> 1;
    const int wc = wave & 1;
    const int tile_r = blockIdx.x >> 6;  // 16 row tiles of 128
    const int tile_c = blockIdx.x & 63;  // 64 col tiles of 128
    const int row0 = tile_r * 128 + wr * 64;
    const int col0 = tile_c * 128 + wc * 64;
    const int l15 = lane & 15;
    const int kg = lane >> 4;

    f32x4 runmax[4][4];
#pragma unroll
    for (int i = 0; i < 4; ++i)
#pragma unroll
        for (int j = 0; j < 4; ++j)
            runmax[i][j] = (f32x4){-3.0e38f, -3.0e38f, -3.0e38f, -3.0e38f};

    const size_t aBase = (size_t)(row0 + l15) * ROWLEN + kg * 8;
    const size_t bBase = (size_t)(col0 + l15) * ROWLEN + kg * 8;

#pragma unroll
    for (int h = 0; h < HEADS; ++h) {
        bf16x8 a[4], b[4];
#pragma unroll
        for (int i = 0; i < 4; ++i)
            a[i] = *(const bf16x8*)(sN + aBase + (size_t)i * 16 * ROWLEN + h * HDIM);
#pragma unroll
        for (int j = 0; j < 4; ++j)
            b[j] = *(const bf16x8*)(roN + bBase + (size_t)j * 16 * ROWLEN + h * HDIM);
#pragma unroll
        for (int i = 0; i < 4; ++i)
#pragma unroll
            for (int j = 0; j < 4; ++j) {
                f32x4 acc = {0.f, 0.f, 0.f, 0.f};
                acc = __builtin_amdgcn_mfma_f32_16x16x32_bf16(a[i], b[j], acc, 0, 0, 0);
#pragma unroll
                for (int q = 0; q < 4; ++q)
                    runmax[i][j][q] = fmaxf(runmax[i][j][q], acc[q]);
            }
    }

#pragma unroll
    for (int i = 0; i < 4; ++i)
#pragma unroll
        for (int j = 0; j < 4; ++j) {
            const int c = col0 + j * 16 + l15;
#pragma unroll
            for (int q = 0; q < 4; ++q) {
                const int r = row0 + i * 16 + kg * 4 + q;
                out[(size_t)r * RO_ROWS + c] = runmax[i][j][q];
            }
        }
}

extern "C" void kernel_launch(void* const* d_in, const int* in_sizes, int n_in,
                              void* d_out, int out_size, void* d_ws, size_t ws_size,
                              hipStream_t stream) {
    const float* batch_s  = (const float*)d_in[0];
    const float* batch_ro = (const float*)d_in[1];
    float* out = (float*)d_out;

    short* sN  = (short*)d_ws;                 // 2048*256 bf16 = 1 MiB
    short* roN = sN + (size_t)S_ROWS * ROWLEN; // 8192*256 bf16 = 4 MiB

    const int totalN = (S_ROWS + RO_ROWS) * ROWLEN;   // 2,621,440 (exact x256)
    mhd_normalize<<<totalN / 256, 256, 0, stream>>>(batch_s, batch_ro, sN);

    mhd_dist<<<(S_ROWS / 128) * (RO_ROWS / 128), 256, 0, stream>>>(sN, roN, out);
}